// Round 1
// baseline (554.533 us; speedup 1.0000x reference)
//
#include <hip/hip_runtime.h>
#include <cstdint>

#define WID   160
#define HEI   160
#define HWPIX (WID * HEI)   // 25600
#define CIN_  64
#define COUT_ 64
#define BATCH 32

// ---------------------------------------------------------------------------
// Kernel 1: weight prep. One block (64 threads = 1 wave) per output channel.
// lane = ci. Produces wpack[co][tap] (bit ci = w>0) and alpha[co] = mean(min(|w|,1)).
// ---------------------------------------------------------------------------
__global__ __launch_bounds__(64) void wprep_kernel(const float* __restrict__ w,
                                                   uint64_t* __restrict__ wpack,
                                                   float* __restrict__ alpha) {
    const int co = blockIdx.x;
    const int ci = threadIdx.x;   // lane == ci
    const float* wp = w + ((size_t)co * CIN_ + ci) * 9;

    float vals[9];
    float s = 0.0f;
#pragma unroll
    for (int t = 0; t < 9; ++t) {
        float v = wp[t];
        vals[t] = v;
        s += fminf(fabsf(v), 1.0f);   // |clip(w,-1,1)|
    }
#pragma unroll
    for (int t = 0; t < 9; ++t) {
        unsigned long long m = __ballot(vals[t] > 0.0f);  // bit ci = sign(+)
        if (ci == 0) wpack[co * 9 + t] = m;
    }
    // wave-64 reduction of s
#pragma unroll
    for (int off = 32; off > 0; off >>= 1) s += __shfl_down(s, off);
    if (ci == 0) alpha[co] = s * (1.0f / 576.0f);
}

// ---------------------------------------------------------------------------
// Kernel 2: binarize + channel-pack. Thread = one pixel (b,y,x); loops ci.
// Loads coalesced along pix per ci iteration. packed[b*HW + pix], bit ci = x>0.
// ---------------------------------------------------------------------------
__global__ __launch_bounds__(256) void binpack_kernel(const float* __restrict__ x,
                                                      uint64_t* __restrict__ packed) {
    const int pix = blockIdx.x * 256 + threadIdx.x;  // 0..25599 (exact)
    const int b   = blockIdx.y;
    const float* xp = x + (size_t)b * CIN_ * HWPIX + pix;

    uint32_t lo = 0, hi = 0;
#pragma unroll
    for (int ci = 0; ci < 32; ++ci)
        lo |= (uint32_t)(xp[(size_t)ci * HWPIX] > 0.0f) << ci;
#pragma unroll
    for (int ci = 0; ci < 32; ++ci)
        hi |= (uint32_t)(xp[(size_t)(ci + 32) * HWPIX] > 0.0f) << ci;

    packed[(size_t)b * HWPIX + pix] = ((uint64_t)hi << 32) | lo;
}

// ---------------------------------------------------------------------------
// Kernel 3: XNOR-popcount conv. grid = (HW/256, COUT, B); thread = one output
// element. co is blockIdx.y -> wpack/alpha loads are wave-uniform (scalar).
// sum over valid taps of (64 - 2*popc(a^w)) = 64*nvalid - 2*sum(popc).
// ---------------------------------------------------------------------------
__global__ __launch_bounds__(256) void conv_kernel(const uint64_t* __restrict__ packed,
                                                   const uint64_t* __restrict__ wpack,
                                                   const float* __restrict__ alpha,
                                                   float* __restrict__ out) {
    const int pix = blockIdx.x * 256 + threadIdx.x;
    const int co  = blockIdx.y;
    const int b   = blockIdx.z;
    const int y   = pix / WID;
    const int x   = pix - y * WID;

    uint64_t wk[9];
#pragma unroll
    for (int t = 0; t < 9; ++t) wk[t] = wpack[co * 9 + t];

    const uint64_t* pb = packed + (size_t)b * HWPIX;

    int pc = 0, nv = 0;
#pragma unroll
    for (int ky = 0; ky < 3; ++ky) {
        const int yy = y + ky - 1;
        if (yy < 0 || yy >= HEI) continue;
        const uint64_t* row = pb + yy * WID;
#pragma unroll
        for (int kx = 0; kx < 3; ++kx) {
            const int xx = x + kx - 1;
            if (xx < 0 || xx >= WID) continue;
            pc += __popcll(row[xx] ^ wk[ky * 3 + kx]);
            ++nv;
        }
    }
    const int s = (nv << 6) - 2 * pc;
    out[((size_t)b * COUT_ + co) * HWPIX + pix] = alpha[co] * (float)s;
}

// ---------------------------------------------------------------------------
extern "C" void kernel_launch(void* const* d_in, const int* in_sizes, int n_in,
                              void* d_out, int out_size, void* d_ws, size_t ws_size,
                              hipStream_t stream) {
    const float* x = (const float*)d_in[0];  // [32,64,160,160] f32
    const float* w = (const float*)d_in[1];  // [64,64,3,3] f32
    float* out = (float*)d_out;              // [32,64,160,160] f32

    // workspace layout
    uint64_t* wpack  = (uint64_t*)d_ws;                          // 64*9*8   = 4608 B
    float*    alpha  = (float*)((char*)d_ws + 4608);             // 256 B
    uint64_t* packed = (uint64_t*)((char*)d_ws + 8192);          // 32*25600*8 = 6.55 MB

    wprep_kernel<<<dim3(COUT_), dim3(64), 0, stream>>>(w, wpack, alpha);
    binpack_kernel<<<dim3(HWPIX / 256, BATCH), dim3(256), 0, stream>>>(x, packed);
    conv_kernel<<<dim3(HWPIX / 256, COUT_, BATCH), dim3(256), 0, stream>>>(packed, wpack, alpha, out);
}

// Round 2
// 446.859 us; speedup vs baseline: 1.2410x; 1.2410x over previous
//
#include <hip/hip_runtime.h>
#include <cstdint>

#define WID   160
#define HEI   160
#define HWPIX (WID * HEI)   // 25600
#define CIN_  64
#define COUT_ 64
#define BATCH 32
#define PW    162           // padded width/height (zero border)
#define PPIX  (PW * PW)     // 26244
#define NBORDER 636         // 2*160 + 2*158 border pixels per image

// ---------------------------------------------------------------------------
// Kernel 1: weight prep. One wave per output channel. lane = ci.
// wpack[co][tap] bit ci = (w>0); alpha[co] = mean(|clip(w,-1,1)|).
// ---------------------------------------------------------------------------
__global__ __launch_bounds__(64) void wprep_kernel(const float* __restrict__ w,
                                                   uint64_t* __restrict__ wpack,
                                                   float* __restrict__ alpha) {
    const int co = blockIdx.x;
    const int ci = threadIdx.x;
    const float* wp = w + ((size_t)co * CIN_ + ci) * 9;

    float vals[9];
    float s = 0.0f;
#pragma unroll
    for (int t = 0; t < 9; ++t) {
        float v = wp[t];
        vals[t] = v;
        s += fminf(fabsf(v), 1.0f);
    }
#pragma unroll
    for (int t = 0; t < 9; ++t) {
        unsigned long long m = __ballot(vals[t] > 0.0f);
        if (ci == 0) wpack[co * 9 + t] = m;
    }
#pragma unroll
    for (int off = 32; off > 0; off >>= 1) s += __shfl_down(s, off);
    if (ci == 0) alpha[co] = s * (1.0f / 576.0f);
}

// ---------------------------------------------------------------------------
// Kernel 2: binarize + channel-pack into zero-padded [b][162][162] u64 layout.
// Thread = 4 consecutive pixels (160%4==0 -> never crosses a row). float4 loads.
// ---------------------------------------------------------------------------
__global__ __launch_bounds__(256) void binpack_kernel(const float* __restrict__ x,
                                                      uint64_t* __restrict__ packed) {
    const int t  = blockIdx.x * 256 + threadIdx.x;   // 0..6399
    const int b  = blockIdx.y;
    const int p4 = t * 4;
    const int y  = p4 / WID;
    const int x0 = p4 - y * WID;
    const float4* xp = (const float4*)(x + (size_t)b * CIN_ * HWPIX + p4);

    uint32_t lo[4] = {0, 0, 0, 0}, hi[4] = {0, 0, 0, 0};
#pragma unroll
    for (int ci = 0; ci < 32; ++ci) {
        float4 v = xp[(size_t)ci * (HWPIX / 4)];
        lo[0] |= (uint32_t)(v.x > 0.0f) << ci;
        lo[1] |= (uint32_t)(v.y > 0.0f) << ci;
        lo[2] |= (uint32_t)(v.z > 0.0f) << ci;
        lo[3] |= (uint32_t)(v.w > 0.0f) << ci;
    }
#pragma unroll
    for (int ci = 0; ci < 32; ++ci) {
        float4 v = xp[(size_t)(ci + 32) * (HWPIX / 4)];
        hi[0] |= (uint32_t)(v.x > 0.0f) << ci;
        hi[1] |= (uint32_t)(v.y > 0.0f) << ci;
        hi[2] |= (uint32_t)(v.z > 0.0f) << ci;
        hi[3] |= (uint32_t)(v.w > 0.0f) << ci;
    }
    uint64_t* dst = packed + (size_t)b * PPIX + (size_t)(y + 1) * PW + (x0 + 1);
#pragma unroll
    for (int i = 0; i < 4; ++i)
        dst[i] = ((uint64_t)hi[i] << 32) | lo[i];
}

// ---------------------------------------------------------------------------
// Kernel 3: main conv. Thread = one pixel; loads 9 padded taps ONCE, loops all
// 64 co with wave-uniform (scalar) weight loads. No bounds checks (zero pad);
// border ring is wrong here and overwritten by fixup_kernel.
// ---------------------------------------------------------------------------
__global__ __launch_bounds__(256) void conv_kernel(const uint64_t* __restrict__ packed,
                                                   const uint64_t* __restrict__ wpack,
                                                   const float* __restrict__ alpha,
                                                   float* __restrict__ out) {
    const int pix = blockIdx.x * 256 + threadIdx.x;
    const int b   = blockIdx.y;
    const int y   = pix / WID;
    const int x   = pix - y * WID;
    // top-left tap in padded coords: (y+1-1, x+1-1) = (y, x)
    const uint64_t* pb = packed + (size_t)b * PPIX + (size_t)y * PW + x;

    uint64_t p[9];
#pragma unroll
    for (int ky = 0; ky < 3; ++ky)
#pragma unroll
        for (int kx = 0; kx < 3; ++kx)
            p[ky * 3 + kx] = pb[(size_t)ky * PW + kx];

    float* op = out + (size_t)b * COUT_ * HWPIX + pix;
#pragma unroll 4
    for (int co = 0; co < COUT_; ++co) {
        int pc = 0;
#pragma unroll
        for (int t = 0; t < 9; ++t)
            pc += __popcll(p[t] ^ wpack[co * 9 + t]);
        const float a = alpha[co];
        op[(size_t)co * HWPIX] = fmaf((float)pc, -2.0f * a, 576.0f * a);
    }
}

// ---------------------------------------------------------------------------
// Kernel 4: exact recompute of the 636-pixel border ring (valid taps only).
// ---------------------------------------------------------------------------
__global__ __launch_bounds__(256) void fixup_kernel(const uint64_t* __restrict__ packed,
                                                    const uint64_t* __restrict__ wpack,
                                                    const float* __restrict__ alpha,
                                                    float* __restrict__ out) {
    const int t = blockIdx.x * 256 + threadIdx.x;
    if (t >= NBORDER * BATCH) return;
    const int b = t / NBORDER;
    const int i = t - b * NBORDER;
    int x, y;
    if      (i < 160) { y = 0;       x = i;       }
    else if (i < 320) { y = 159;     x = i - 160; }
    else if (i < 478) { x = 0;       y = i - 319; }  // y = 1..158
    else              { x = 159;     y = i - 477; }  // y = 1..158

    const uint64_t* pb = packed + (size_t)b * PPIX + (size_t)y * PW + x;
    uint64_t p[9];
    int valid[9];
    int nv = 0;
#pragma unroll
    for (int ky = 0; ky < 3; ++ky)
#pragma unroll
        for (int kx = 0; kx < 3; ++kx) {
            const int yy = y + ky - 1, xx = x + kx - 1;
            const int v = (yy >= 0) && (yy < HEI) && (xx >= 0) && (xx < WID);
            valid[ky * 3 + kx] = v;
            nv += v;
            p[ky * 3 + kx] = pb[(size_t)ky * PW + kx];  // pad region: harmless read
        }
    float* op = out + (size_t)b * COUT_ * HWPIX + (size_t)y * WID + x;
    for (int co = 0; co < COUT_; ++co) {
        int pc = 0;
#pragma unroll
        for (int tt = 0; tt < 9; ++tt)
            pc += valid[tt] ? __popcll(p[tt] ^ wpack[co * 9 + tt]) : 0;
        op[(size_t)co * HWPIX] = alpha[co] * (float)((nv << 6) - 2 * pc);
    }
}

// ---------------------------------------------------------------------------
extern "C" void kernel_launch(void* const* d_in, const int* in_sizes, int n_in,
                              void* d_out, int out_size, void* d_ws, size_t ws_size,
                              hipStream_t stream) {
    const float* x = (const float*)d_in[0];  // [32,64,160,160] f32
    const float* w = (const float*)d_in[1];  // [64,64,3,3] f32
    float* out = (float*)d_out;              // [32,64,160,160] f32

    uint64_t* wpack  = (uint64_t*)d_ws;                      // 4608 B
    float*    alpha  = (float*)((char*)d_ws + 4608);         // 256 B
    uint64_t* packed = (uint64_t*)((char*)d_ws + 8192);      // 32*26244*8 = 6.72 MB

    // zero padded packed buffer (ws is re-poisoned 0xAA before every call)
    hipMemsetAsync(packed, 0, (size_t)BATCH * PPIX * sizeof(uint64_t), stream);

    wprep_kernel<<<dim3(COUT_), dim3(64), 0, stream>>>(w, wpack, alpha);
    binpack_kernel<<<dim3(HWPIX / 4 / 256, BATCH), dim3(256), 0, stream>>>(x, packed);
    conv_kernel<<<dim3(HWPIX / 256, BATCH), dim3(256), 0, stream>>>(packed, wpack, alpha, out);
    fixup_kernel<<<dim3((NBORDER * BATCH + 255) / 256), dim3(256), 0, stream>>>(packed, wpack, alpha, out);
}